// Round 20
// baseline (230.778 us; speedup 1.0000x reference)
//
#include <hip/hip_runtime.h>
#include <stdint.h>

#define BN_ 8192
#define DK_ 256
#define LOG2E 1.4426950408889634f
// int8 quantization: q = round(127*x); dot fits i32 exactly
#define INVQ (1.0f / 16129.0f)          // 1/127^2: acc -> natural-units sim
#define KQ   (LOG2E / 16129.0f)          // acc -> log2-units sim

typedef __attribute__((ext_vector_type(4))) float f32x4;
typedef __attribute__((ext_vector_type(4))) int i32x4;

// async global->LDS, 16B/lane; LDS dest wave-uniform base + lane*16, global src per-lane
#define GLD16(gp, lp)                                                   \
  __builtin_amdgcn_global_load_lds(                                     \
      (__attribute__((address_space(1))) void*)(gp),                    \
      (__attribute__((address_space(3))) void*)(lp), 16, 0, 0)

#define BAR() __builtin_amdgcn_s_barrier()
#define VM4() asm volatile("s_waitcnt vmcnt(4)" ::: "memory")
#define VM0() asm volatile("s_waitcnt vmcnt(0)" ::: "memory")

// ---------------- Kernel 1: row-normalize fp32 -> int8 (x127); also zeroes sumexp ----------------
__global__ __launch_bounds__(256) void norm_kernel(
    const float* __restrict__ hf, const float* __restrict__ lf,
    const float* __restrict__ af, unsigned char* __restrict__ qbase,
    float* __restrict__ sumexp) {
  const int tid = threadIdx.x;
  if (blockIdx.x < 16) {   // folded memset of sumexp[16384]
    f32x4 z = {0.f, 0.f, 0.f, 0.f};
    *(f32x4*)(sumexp + blockIdx.x * 1024 + tid * 4) = z;
  }
  const int w = tid >> 6, lane = tid & 63;
  const int grow = blockIdx.x * 4 + w;
  const int m = grow >> 13;
  const int r = grow & (BN_ - 1);
  const float* src = (m == 0) ? hf : (m == 1) ? lf : af;
  unsigned char* dst = qbase + (size_t)m * BN_ * DK_;
  const float4 v = ((const float4*)(src + (size_t)r * DK_))[lane];
  float ss = v.x * v.x + v.y * v.y + v.z * v.z + v.w * v.w;
#pragma unroll
  for (int mk = 32; mk >= 1; mk >>= 1) ss += __shfl_xor(ss, mk, 64);
  const float inv = 127.0f / fmaxf(sqrtf(ss), 1e-8f);
  const int q0 = (int)rintf(v.x * inv), q1 = (int)rintf(v.y * inv);
  const int q2 = (int)rintf(v.z * inv), q3 = (int)rintf(v.w * inv);
  const unsigned pk = (q0 & 255) | ((q1 & 255) << 8) | ((q2 & 255) << 16) |
                      ((unsigned)(q3 & 255) << 24);
  *(unsigned*)(dst + (size_t)r * DK_ + lane * 4) = pk;
}

// ---------------- Kernel 2: barrier-free int8-GEMM + exp2-row-sum + diag ----------------
// R19 structure (proven) at HALF block size for 2-blocks/CU co-residency:
// 512 blocks = 256 mt (64-row A panels) x 2 cg (4096-col halves).
// 8 waves (2wr x 4wc), wave tile 32x64. A panel 16KB staged once (the only
// barrier), A frags hoisted (afr[4][2], 32 VGPR). Private per-wave B
// double-buffer 8KB, vmcnt(4)-gated, ZERO main-loop barriers (R19 ledger).
// LDS 16+64 = 80KB -> 2 blocks/CU; VGPR ~110 <= 128 -> 4 waves/SIMD: twice
// the independent instruction streams per SIMD to fill VALU+MFMA+LDS pipes
// (R19: 42%+27% busy, 31% latency-idle at 2 waves/SIMD).
__global__ __launch_bounds__(512, 2) void gemm_lse_kernel(
    const unsigned char* __restrict__ hl, const unsigned char* __restrict__ an,
    float* __restrict__ sumexp /*[16384]*/, float* __restrict__ diag /*[16384]*/) {
  extern __shared__ char lds[];  // 80KB

  const int tid = threadIdx.x;
  const int lane = tid & 63, w = tid >> 6;
  const int wr = w >> 2, wc = w & 3;
  const int lmod = lane & 15, lhalf = lane >> 4;

  const int bid = blockIdx.x;
  const int swz = (bid & 7) * 64 + (bid >> 3);  // bijective on 512, XCD-grouping
  const int mt = swz >> 1;                      // A panel 0..255 (64 rows each)
  const int cg = swz & 1;                       // col half (16 ct of 256 cols)

  // ---- A cooperative stage: 64 rows x 16 slots, phys16 = s ^ (row&15) ----
  const int aswz = 16 * ((tid & 15) ^ ((tid >> 4) & 15));
  const unsigned char* aG = hl + (size_t)(mt * 64 + (tid >> 4)) * DK_ + aswz;
  char* aD = lds + tid * 16;
  GLD16(aG, aD);                 // rows 0..31
  GLD16(aG + 8192, aD + 8192);   // rows 32..63

  // ---- B private staging constants (R16-verified 64-row slice layout) ----
  const int slog16 = 16 * ((lane & 3) ^ ((lane >> 3) & 3));
  const unsigned char* bB =
      an + (size_t)(cg * 4096 + wc * 64 + (lane >> 2)) * DK_ + slog16;
  char* ldsB = lds + 16384 + w * 8192 + lane * 16;

#define STAGEB(uu)                                                       \
  do {                                                                   \
    const int ct_ = (uu) >> 2, ku_ = (uu) & 3;                           \
    const unsigned char* g_ = bB + ct_ * 65536 + ku_ * 64;               \
    char* d_ = ldsB + ((uu) & 1) * 4096;                                 \
    GLD16(g_, d_);                                                       \
    GLD16(g_ + 4096, d_ + 1024);                                         \
    GLD16(g_ + 8192, d_ + 2048);                                         \
    GLD16(g_ + 12288, d_ + 3072);                                        \
  } while (0)

  STAGEB(0);
  VM4();   // 6 outstanding (2 A + 4 B0) -> <=4 left: both A loads retired
  BAR();   // the kernel's ONLY barrier: A collectively resident

  // ---- hoist A frags: afr[ku][m], row = wr*32 + m*16 + lmod (row&15==lmod) ----
  i32x4 afr[4][2];
  {
    const char* aR = lds + (wr * 32 + lmod) * 256;
#pragma unroll
    for (int ku = 0; ku < 4; ++ku)
#pragma unroll
      for (int m = 0; m < 2; ++m)
        afr[ku][m] = *(const i32x4*)(aR + m * 4096 + 16 * ((ku * 4 + lhalf) ^ lmod));
  }

  const int rdoffB = lmod * 64 + 16 * (lhalf ^ ((lmod >> 1) & 3));
  const char* ldsBr = lds + 16384 + w * 8192;

  // ---- diag geometry: block rows R0..R0+63 (64-aligned) ----
  const int p = mt >> 7;
  const int R0 = (mt & 127) * 64;
  const bool dWave = (cg == (R0 >> 12)) && (wc == ((R0 >> 6) & 3));
  const int ctD = (R0 & 4095) >> 8;

  float rsum[2][4];
#pragma unroll
  for (int m = 0; m < 2; ++m)
#pragma unroll
    for (int r = 0; r < 4; ++r) rsum[m][r] = 0.0f;

#pragma unroll 1
  for (int ct = 0; ct < 16; ++ct) {
    i32x4 acc[2][4];
#pragma unroll
    for (int m = 0; m < 2; ++m)
#pragma unroll
      for (int n = 0; n < 4; ++n) acc[m][n] = i32x4{0, 0, 0, 0};

#pragma unroll
    for (int ku = 0; ku < 4; ++ku) {
      const int u = ct * 4 + ku;
      if (u < 63) {
        STAGEB(u + 1);
        VM4();   // my B(u) landed (only B(u+1)'s 4 loads may remain)
      } else {
        VM0();   // last unit
      }
      const char* Lb = ldsBr + (ku & 1) * 4096;
      i32x4 bf[4];
#pragma unroll
      for (int n = 0; n < 4; ++n) bf[n] = *(const i32x4*)(Lb + n * 1024 + rdoffB);
      __builtin_amdgcn_s_setprio(1);
#pragma unroll
      for (int m = 0; m < 2; ++m)
#pragma unroll
        for (int n = 0; n < 4; ++n)
          acc[m][n] = __builtin_amdgcn_mfma_i32_16x16x64_i8(afr[ku][m], bf[n], acc[m][n], 0, 0, 0);
      __builtin_amdgcn_s_setprio(0);
    }

    // ---- tile epilogue: diag (rare) + exp2 into persistent rsum ----
    if (dWave && ct == ctD) {
      // wave cols == R0..R0+63; row wr*32+m*16+lrow == col n*16+lmod
      // requires n = wr*2+m and lmod == lhalf*4+r
#pragma unroll
      for (int m = 0; m < 2; ++m)
#pragma unroll
        for (int r = 0; r < 4; ++r)
          if (lmod == lhalf * 4 + r)
            diag[p * BN_ + R0 + wr * 32 + m * 16 + lmod] =
                (float)acc[m][wr * 2 + m][r] * INVQ;
    }
#pragma unroll
    for (int m = 0; m < 2; ++m)
#pragma unroll
      for (int n = 0; n < 4; ++n)
#pragma unroll
        for (int r = 0; r < 4; ++r)
          rsum[m][r] += __builtin_amdgcn_exp2f((float)acc[m][n][r] * KQ);
  }

  // ---- final: reduce across 16 col-lanes, then atomicAdd (4 wc waves + 2 cg blocks per row) ----
#pragma unroll
  for (int m = 0; m < 2; ++m)
#pragma unroll
    for (int r = 0; r < 4; ++r) {
      float v = rsum[m][r];
      v += __shfl_xor(v, 1, 64);
      v += __shfl_xor(v, 2, 64);
      v += __shfl_xor(v, 4, 64);
      v += __shfl_xor(v, 8, 64);
      if (lmod == 0)
        atomicAdd(&sumexp[p * BN_ + R0 + wr * 32 + m * 16 + lhalf * 4 + r], v);
    }
#undef STAGEB
}

// ---------------- Kernel 3: CE = mean(log(sumexp) - diag) ----------------
__global__ __launch_bounds__(1024) void finalize_kernel(
    const float* __restrict__ sumexp, const float* __restrict__ diag,
    float* __restrict__ out) {
  const int tid = threadIdx.x;
  float s = 0.0f;
  for (int i = tid; i < 2 * BN_; i += 1024) s += logf(sumexp[i]) - diag[i];
#pragma unroll
  for (int mk = 32; mk >= 1; mk >>= 1) s += __shfl_xor(s, mk, 64);
  __shared__ float red[16];
  if ((tid & 63) == 0) red[tid >> 6] = s;
  __syncthreads();
  if (tid == 0) {
    float t = 0.f;
#pragma unroll
    for (int j = 0; j < 16; ++j) t += red[j];
    out[0] = t * (1.0f / (float)BN_);
  }
}

extern "C" void kernel_launch(void* const* d_in, const int* in_sizes, int n_in,
                              void* d_out, int out_size, void* d_ws, size_t ws_size,
                              hipStream_t stream) {
  const float* hf = (const float*)d_in[0];
  const float* lf = (const float*)d_in[1];
  const float* af = (const float*)d_in[2];

  char* ws = (char*)d_ws;
  const size_t nmat = (size_t)BN_ * DK_;                 // 2MB as i8
  unsigned char* qbase = (unsigned char*)ws;             // hq(2MB) lq(2MB) aq(2MB)
  unsigned char* hl = qbase;                             // stacked A [16384][256]
  unsigned char* an = qbase + 2 * nmat;
  float* sumexp = (float*)(ws + 3 * nmat);               // 64 KB [16384]
  float* diag = sumexp + 2 * BN_;                        // 64 KB [16384]

  hipFuncSetAttribute((const void*)gemm_lse_kernel,
                      hipFuncAttributeMaxDynamicSharedMemorySize, 81920);

  norm_kernel<<<(3 * BN_) / 4, 256, 0, stream>>>(hf, lf, af, qbase, sumexp);
  gemm_lse_kernel<<<512, 512, 81920, stream>>>(hl, an, sumexp, diag);
  finalize_kernel<<<1, 1024, 0, stream>>>(sumexp, diag, (float*)d_out);
}

// Round 21
// 86.089 us; speedup vs baseline: 2.6807x; 2.6807x over previous
//
#include <hip/hip_runtime.h>
#include <stdint.h>

#define BN_ 8192
#define DK_ 256
#define LOG2E 1.4426950408889634f
// int8 quantization: q = round(127*x); dot fits i32 exactly
#define INVQ (1.0f / 16129.0f)          // 1/127^2: acc -> natural-units sim
#define KQ   (LOG2E / 16129.0f)          // acc -> log2-units sim

typedef __attribute__((ext_vector_type(4))) float f32x4;
typedef __attribute__((ext_vector_type(4))) int i32x4;

// async global->LDS, 16B/lane; LDS dest wave-uniform base + lane*16, global src per-lane
#define GLD16(gp, lp)                                                   \
  __builtin_amdgcn_global_load_lds(                                     \
      (__attribute__((address_space(1))) void*)(gp),                    \
      (__attribute__((address_space(3))) void*)(lp), 16, 0, 0)

#define BAR() __builtin_amdgcn_s_barrier()
#define VM4() asm volatile("s_waitcnt vmcnt(4)" ::: "memory")
#define VM0() asm volatile("s_waitcnt vmcnt(0)" ::: "memory")

// ---------------- Kernel 1: row-normalize fp32 -> int8 (x127); also zeroes sumexp ----------------
__global__ __launch_bounds__(256) void norm_kernel(
    const float* __restrict__ hf, const float* __restrict__ lf,
    const float* __restrict__ af, unsigned char* __restrict__ qbase,
    float* __restrict__ sumexp) {
  const int tid = threadIdx.x;
  if (blockIdx.x < 16) {   // folded memset of sumexp[16384]
    f32x4 z = {0.f, 0.f, 0.f, 0.f};
    *(f32x4*)(sumexp + blockIdx.x * 1024 + tid * 4) = z;
  }
  const int w = tid >> 6, lane = tid & 63;
  const int grow = blockIdx.x * 4 + w;
  const int m = grow >> 13;
  const int r = grow & (BN_ - 1);
  const float* src = (m == 0) ? hf : (m == 1) ? lf : af;
  unsigned char* dst = qbase + (size_t)m * BN_ * DK_;
  const float4 v = ((const float4*)(src + (size_t)r * DK_))[lane];
  float ss = v.x * v.x + v.y * v.y + v.z * v.z + v.w * v.w;
#pragma unroll
  for (int mk = 32; mk >= 1; mk >>= 1) ss += __shfl_xor(ss, mk, 64);
  const float inv = 127.0f / fmaxf(sqrtf(ss), 1e-8f);
  const int q0 = (int)rintf(v.x * inv), q1 = (int)rintf(v.y * inv);
  const int q2 = (int)rintf(v.z * inv), q3 = (int)rintf(v.w * inv);
  const unsigned pk = (q0 & 255) | ((q1 & 255) << 8) | ((q2 & 255) << 16) |
                      ((unsigned)(q3 & 255) << 24);
  *(unsigned*)(dst + (size_t)r * DK_ + lane * 4) = pk;
}

// ---------------- Kernel 2: barrier-free int8-GEMM + exp2-row-sum + diag ----------------
// R20 structure (2 blocks/CU co-residency -- occupancy 32% CONFIRMED in R20)
// with the rule-#20 fix: diag indexing must be COMPILE-TIME. R20's
// acc[m][wr*2+m] (runtime wr) demoted acc to scratch: VGPR 60, WRITE 534MB,
// 226us. Fix: wave-uniform branch on wr with unrolled compile-time indices.
// 512 blocks = 256 mt (64-row A panels) x 2 cg; 8 waves (2wr x 4wc), wave
// tile 32x64; A 16KB staged once (only barrier), afr[4][2] hoisted; private
// per-wave 8KB B double-buffer, vmcnt(4)-gated, zero main-loop barriers.
__global__ __launch_bounds__(512, 2) void gemm_lse_kernel(
    const unsigned char* __restrict__ hl, const unsigned char* __restrict__ an,
    float* __restrict__ sumexp /*[16384]*/, float* __restrict__ diag /*[16384]*/) {
  extern __shared__ char lds[];  // 80KB

  const int tid = threadIdx.x;
  const int lane = tid & 63, w = tid >> 6;
  const int wr = w >> 2, wc = w & 3;
  const int lmod = lane & 15, lhalf = lane >> 4;

  const int bid = blockIdx.x;
  const int swz = (bid & 7) * 64 + (bid >> 3);  // bijective on 512, XCD-grouping
  const int mt = swz >> 1;                      // A panel 0..255 (64 rows each)
  const int cg = swz & 1;                       // col half (16 ct of 256 cols)

  // ---- A cooperative stage: 64 rows x 16 slots, phys16 = s ^ (row&15) ----
  const int aswz = 16 * ((tid & 15) ^ ((tid >> 4) & 15));
  const unsigned char* aG = hl + (size_t)(mt * 64 + (tid >> 4)) * DK_ + aswz;
  char* aD = lds + tid * 16;
  GLD16(aG, aD);                 // rows 0..31
  GLD16(aG + 8192, aD + 8192);   // rows 32..63

  // ---- B private staging constants (R16-verified 64-row slice layout) ----
  const int slog16 = 16 * ((lane & 3) ^ ((lane >> 3) & 3));
  const unsigned char* bB =
      an + (size_t)(cg * 4096 + wc * 64 + (lane >> 2)) * DK_ + slog16;
  char* ldsB = lds + 16384 + w * 8192 + lane * 16;

#define STAGEB(uu)                                                       \
  do {                                                                   \
    const int ct_ = (uu) >> 2, ku_ = (uu) & 3;                           \
    const unsigned char* g_ = bB + ct_ * 65536 + ku_ * 64;               \
    char* d_ = ldsB + ((uu) & 1) * 4096;                                 \
    GLD16(g_, d_);                                                       \
    GLD16(g_ + 4096, d_ + 1024);                                         \
    GLD16(g_ + 8192, d_ + 2048);                                         \
    GLD16(g_ + 12288, d_ + 3072);                                        \
  } while (0)

  STAGEB(0);
  VM4();   // 6 outstanding (2 A + 4 B0) -> <=4 left: both A loads retired
  BAR();   // the kernel's ONLY barrier: A collectively resident

  // ---- hoist A frags: afr[ku][m], row = wr*32 + m*16 + lmod (row&15==lmod) ----
  i32x4 afr[4][2];
  {
    const char* aR = lds + (wr * 32 + lmod) * 256;
#pragma unroll
    for (int ku = 0; ku < 4; ++ku)
#pragma unroll
      for (int m = 0; m < 2; ++m)
        afr[ku][m] = *(const i32x4*)(aR + m * 4096 + 16 * ((ku * 4 + lhalf) ^ lmod));
  }

  const int rdoffB = lmod * 64 + 16 * (lhalf ^ ((lmod >> 1) & 3));
  const char* ldsBr = lds + 16384 + w * 8192;

  // ---- diag geometry: block rows R0..R0+63 (64-aligned) ----
  const int p = mt >> 7;
  const int R0 = (mt & 127) * 64;
  const bool dWave = (cg == (R0 >> 12)) && (wc == ((R0 >> 6) & 3));
  const int ctD = (R0 & 4095) >> 8;

  float rsum[2][4];
#pragma unroll
  for (int m = 0; m < 2; ++m)
#pragma unroll
    for (int r = 0; r < 4; ++r) rsum[m][r] = 0.0f;

#pragma unroll 1
  for (int ct = 0; ct < 16; ++ct) {
    i32x4 acc[2][4];
#pragma unroll
    for (int m = 0; m < 2; ++m)
#pragma unroll
      for (int n = 0; n < 4; ++n) acc[m][n] = i32x4{0, 0, 0, 0};

#pragma unroll
    for (int ku = 0; ku < 4; ++ku) {
      const int u = ct * 4 + ku;
      if (u < 63) {
        STAGEB(u + 1);
        VM4();   // my B(u) landed (only B(u+1)'s 4 loads may remain)
      } else {
        VM0();   // last unit
      }
      const char* Lb = ldsBr + (ku & 1) * 4096;
      i32x4 bf[4];
#pragma unroll
      for (int n = 0; n < 4; ++n) bf[n] = *(const i32x4*)(Lb + n * 1024 + rdoffB);
      __builtin_amdgcn_s_setprio(1);
#pragma unroll
      for (int m = 0; m < 2; ++m)
#pragma unroll
        for (int n = 0; n < 4; ++n)
          acc[m][n] = __builtin_amdgcn_mfma_i32_16x16x64_i8(afr[ku][m], bf[n], acc[m][n], 0, 0, 0);
      __builtin_amdgcn_s_setprio(0);
    }

    // ---- tile epilogue: diag (rare) + exp2 into persistent rsum ----
    // row wr*32+m*16+lrow == col n*16+lmod requires n = wr*2+m and
    // lmod == lhalf*4+r. Rule #20: keep acc indices COMPILE-TIME -- branch
    // on wave-uniform wr instead of computing n at runtime (R20 bug).
    if (dWave && ct == ctD) {
      if (wr == 0) {
#pragma unroll
        for (int m = 0; m < 2; ++m)
#pragma unroll
          for (int r = 0; r < 4; ++r)
            if (lmod == lhalf * 4 + r)
              diag[p * BN_ + R0 + m * 16 + lmod] = (float)acc[m][m][r] * INVQ;
      } else {
#pragma unroll
        for (int m = 0; m < 2; ++m)
#pragma unroll
          for (int r = 0; r < 4; ++r)
            if (lmod == lhalf * 4 + r)
              diag[p * BN_ + R0 + 32 + m * 16 + lmod] = (float)acc[m][2 + m][r] * INVQ;
      }
    }
#pragma unroll
    for (int m = 0; m < 2; ++m)
#pragma unroll
      for (int n = 0; n < 4; ++n)
#pragma unroll
        for (int r = 0; r < 4; ++r)
          rsum[m][r] += __builtin_amdgcn_exp2f((float)acc[m][n][r] * KQ);
  }

  // ---- final: reduce across 16 col-lanes, then atomicAdd (4 wc waves + 2 cg blocks per row) ----
#pragma unroll
  for (int m = 0; m < 2; ++m)
#pragma unroll
    for (int r = 0; r < 4; ++r) {
      float v = rsum[m][r];
      v += __shfl_xor(v, 1, 64);
      v += __shfl_xor(v, 2, 64);
      v += __shfl_xor(v, 4, 64);
      v += __shfl_xor(v, 8, 64);
      if (lmod == 0)
        atomicAdd(&sumexp[p * BN_ + R0 + wr * 32 + m * 16 + lhalf * 4 + r], v);
    }
#undef STAGEB
}

// ---------------- Kernel 3: CE = mean(log(sumexp) - diag) ----------------
__global__ __launch_bounds__(1024) void finalize_kernel(
    const float* __restrict__ sumexp, const float* __restrict__ diag,
    float* __restrict__ out) {
  const int tid = threadIdx.x;
  float s = 0.0f;
  for (int i = tid; i < 2 * BN_; i += 1024) s += logf(sumexp[i]) - diag[i];
#pragma unroll
  for (int mk = 32; mk >= 1; mk >>= 1) s += __shfl_xor(s, mk, 64);
  __shared__ float red[16];
  if ((tid & 63) == 0) red[tid >> 6] = s;
  __syncthreads();
  if (tid == 0) {
    float t = 0.f;
#pragma unroll
    for (int j = 0; j < 16; ++j) t += red[j];
    out[0] = t * (1.0f / (float)BN_);
  }
}

extern "C" void kernel_launch(void* const* d_in, const int* in_sizes, int n_in,
                              void* d_out, int out_size, void* d_ws, size_t ws_size,
                              hipStream_t stream) {
  const float* hf = (const float*)d_in[0];
  const float* lf = (const float*)d_in[1];
  const float* af = (const float*)d_in[2];

  char* ws = (char*)d_ws;
  const size_t nmat = (size_t)BN_ * DK_;                 // 2MB as i8
  unsigned char* qbase = (unsigned char*)ws;             // hq(2MB) lq(2MB) aq(2MB)
  unsigned char* hl = qbase;                             // stacked A [16384][256]
  unsigned char* an = qbase + 2 * nmat;
  float* sumexp = (float*)(ws + 3 * nmat);               // 64 KB [16384]
  float* diag = sumexp + 2 * BN_;                        // 64 KB [16384]

  hipFuncSetAttribute((const void*)gemm_lse_kernel,
                      hipFuncAttributeMaxDynamicSharedMemorySize, 81920);

  norm_kernel<<<(3 * BN_) / 4, 256, 0, stream>>>(hf, lf, af, qbase, sumexp);
  gemm_lse_kernel<<<512, 512, 81920, stream>>>(hl, an, sumexp, diag);
  finalize_kernel<<<1, 1024, 0, stream>>>(sumexp, diag, (float*)d_out);
}

// Round 22
// 66.750 us; speedup vs baseline: 3.4574x; 1.2897x over previous
//
#include <hip/hip_runtime.h>
#include <stdint.h>

#define BN_ 8192
#define DK_ 256
#define LOG2E 1.4426950408889634f
// int8 quantization: q = round(127*x); dot fits i32 exactly
#define INVQ (1.0f / 16129.0f)          // 1/127^2: acc -> natural-units sim
#define KQ   (LOG2E / 16129.0f)          // acc -> log2-units sim

typedef __attribute__((ext_vector_type(4))) float f32x4;
typedef __attribute__((ext_vector_type(4))) int i32x4;

// async global->LDS, 16B/lane; LDS dest wave-uniform base + lane*16, global src per-lane
#define GLD16(gp, lp)                                                   \
  __builtin_amdgcn_global_load_lds(                                     \
      (__attribute__((address_space(1))) void*)(gp),                    \
      (__attribute__((address_space(3))) void*)(lp), 16, 0, 0)

#define BAR() __builtin_amdgcn_s_barrier()
#define VM4() asm volatile("s_waitcnt vmcnt(4)" ::: "memory")
#define VM0() asm volatile("s_waitcnt vmcnt(0)" ::: "memory")

// ---------------- Kernel 1: row-normalize fp32 -> int8 (x127); also zeroes sumexp ----------------
__global__ __launch_bounds__(256) void norm_kernel(
    const float* __restrict__ hf, const float* __restrict__ lf,
    const float* __restrict__ af, unsigned char* __restrict__ qbase,
    float* __restrict__ sumexp) {
  const int tid = threadIdx.x;
  if (blockIdx.x < 16) {   // folded memset of sumexp[16384]
    f32x4 z = {0.f, 0.f, 0.f, 0.f};
    *(f32x4*)(sumexp + blockIdx.x * 1024 + tid * 4) = z;
  }
  const int w = tid >> 6, lane = tid & 63;
  const int grow = blockIdx.x * 4 + w;
  const int m = grow >> 13;
  const int r = grow & (BN_ - 1);
  const float* src = (m == 0) ? hf : (m == 1) ? lf : af;
  unsigned char* dst = qbase + (size_t)m * BN_ * DK_;
  const float4 v = ((const float4*)(src + (size_t)r * DK_))[lane];
  float ss = v.x * v.x + v.y * v.y + v.z * v.z + v.w * v.w;
#pragma unroll
  for (int mk = 32; mk >= 1; mk >>= 1) ss += __shfl_xor(ss, mk, 64);
  const float inv = 127.0f / fmaxf(sqrtf(ss), 1e-8f);
  const int q0 = (int)rintf(v.x * inv), q1 = (int)rintf(v.y * inv);
  const int q2 = (int)rintf(v.z * inv), q3 = (int)rintf(v.w * inv);
  const unsigned pk = (q0 & 255) | ((q1 & 255) << 8) | ((q2 & 255) << 16) |
                      ((unsigned)(q3 & 255) << 24);
  *(unsigned*)(dst + (size_t)r * DK_ + lane * 4) = pk;
}

// ---------------- Kernel 2: barrier-free int8-GEMM + exp2-row-sum + diag ----------------
// R19 geometry (champion, 52.3us) + intra-wave B-fragment register double
// buffer over a 3-slot LDS queue. Per unit:
//   {STAGEB(u+2)->slot (u+2)%3; VM4 (B(u+1) resident); ds_read bfn(u+1);
//    MFMA(u) with bfc (regs only -- independent of the new reads)}
// The bf ds_reads now run on the LDS pipe UNDER the MFMA cluster; R19's VM4
// memory clobber had forced read->MFMA serialization every unit (~140cy
// exposed LDS latency x 64 units). Slot ledger (period 3): stage(u+2) hits
// the slot last ds_read at iter u-1 (2-iter WAR gap); VM4 leaves <=4
// outstanding -> B(u+1) retired (in-order). Tail ct=15 peeled, VM0 at u=62.
// 256 blocks = 128 mt x 2 cg; 8 waves (2wr x 4wc), wave tile 64x64;
// A panel 32KB staged once (only barrier), afr[4][4] hoisted.
// LDS: A 32KB + 8 waves x 12KB = 128KB (1 block/CU).
__global__ __launch_bounds__(512, 2) void gemm_lse_kernel(
    const unsigned char* __restrict__ hl, const unsigned char* __restrict__ an,
    float* __restrict__ sumexp /*[16384]*/, float* __restrict__ diag /*[16384]*/) {
  extern __shared__ char lds[];  // 128KB

  const int tid = threadIdx.x;
  const int lane = tid & 63, w = tid >> 6;
  const int wr = w >> 2, wc = w & 3;
  const int lmod = lane & 15, lhalf = lane >> 4;

  const int bid = blockIdx.x;
  const int swz = (bid & 7) * 32 + (bid >> 3);  // bijective on 256, XCD-grouping
  const int mt = swz >> 1;                      // row panel 0..127 (128 rows each)
  const int cg = swz & 1;                       // col half (16 ct of 256 cols)

  // ---- A cooperative stage: [128 rows][16 slots], phys16 = s ^ (row&15) ----
  const int aswz = 16 * ((tid & 15) ^ ((tid >> 4) & 15));
  const unsigned char* aG = hl + (size_t)(mt * 128 + (tid >> 4)) * DK_ + aswz;
  char* aD = lds + tid * 16;
  GLD16(aG, aD);
  GLD16(aG + 8192, aD + 8192);
  GLD16(aG + 16384, aD + 16384);
  GLD16(aG + 24576, aD + 24576);

  // ---- B private staging constants (R16/R19-verified 64-row slice layout) ----
  const int slog16 = 16 * ((lane & 3) ^ ((lane >> 3) & 3));
  const unsigned char* bB =
      an + (size_t)(cg * 4096 + wc * 64 + (lane >> 2)) * DK_ + slog16;
  char* bw = lds + 32768 + w * 12288;   // this wave's 3-slot region
  char* c0 = bw;                         // slot ptrs rotate per ct
  char* c1 = bw + 4096;
  char* c2 = bw + 8192;

#define STAGEB(uu, DST)                                                  \
  do {                                                                   \
    const int ct_ = (uu) >> 2, ku_ = (uu) & 3;                           \
    const unsigned char* g_ = bB + ct_ * 65536 + ku_ * 64;               \
    char* d_ = (DST) + lane * 16;                                        \
    GLD16(g_, d_);                                                       \
    GLD16(g_ + 4096, d_ + 1024);                                         \
    GLD16(g_ + 8192, d_ + 2048);                                         \
    GLD16(g_ + 12288, d_ + 3072);                                        \
  } while (0)

  STAGEB(0, c0);
  STAGEB(1, c1);
  VM4();   // 12 outstanding (4A+4B0+4B1) -> <=4 left: A and B0 retired
  BAR();   // the kernel's ONLY barrier: A collectively resident

  // ---- hoist all A fragments (R19-verified formulas) ----
  i32x4 afr[4][4];
  {
    const char* aR = lds + (wr * 64 + lmod) * 256;
#pragma unroll
    for (int ku = 0; ku < 4; ++ku)
#pragma unroll
      for (int m = 0; m < 4; ++m)
        afr[ku][m] = *(const i32x4*)(aR + m * 4096 + 16 * ((ku * 4 + lhalf) ^ lmod));
  }

  const int rdoffB = lmod * 64 + 16 * (lhalf ^ ((lmod >> 1) & 3));

  i32x4 bfc[4], bfn[4];
#pragma unroll
  for (int n = 0; n < 4; ++n)
    bfc[n] = *(const i32x4*)(c0 + n * 1024 + rdoffB);   // bf(0)

#define RDNXT(SRC)                                                       \
  _Pragma("unroll") for (int n = 0; n < 4; ++n)                          \
      bfn[n] = *(const i32x4*)((SRC) + n * 1024 + rdoffB)

#define CPB()                                                            \
  _Pragma("unroll") for (int n = 0; n < 4; ++n) bfc[n] = bfn[n]

#define MFMA16(KU)                                                       \
  __builtin_amdgcn_s_setprio(1);                                         \
  _Pragma("unroll") for (int m = 0; m < 4; ++m)                          \
  _Pragma("unroll") for (int n = 0; n < 4; ++n)                          \
      acc[m][n] = __builtin_amdgcn_mfma_i32_16x16x64_i8(                 \
          afr[KU][m], bfc[n], acc[m][n], 0, 0, 0);                       \
  __builtin_amdgcn_s_setprio(0)

  // ---- diag geometry (R19-verified) ----
  const int p = mt >> 6;
  const int D = (mt & 63) * 128 + wr * 64;
  const bool dWave = (wc == ((D >> 6) & 3)) && ((D >> 12) == cg);
  const int ctD = (D >> 8) & 15;

  float rsum[4][4];
#pragma unroll
  for (int m = 0; m < 4; ++m)
#pragma unroll
    for (int r = 0; r < 4; ++r) rsum[m][r] = 0.0f;

#pragma unroll 1
  for (int ct = 0; ct < 16; ++ct) {
    i32x4 acc[4][4];
#pragma unroll
    for (int m = 0; m < 4; ++m)
#pragma unroll
      for (int n = 0; n < 4; ++n) acc[m][n] = i32x4{0, 0, 0, 0};

    const int u0 = ct * 4;
    if (ct < 15) {
      STAGEB(u0 + 2, c2); VM4(); RDNXT(c1); MFMA16(0); CPB();
      STAGEB(u0 + 3, c0); VM4(); RDNXT(c2); MFMA16(1); CPB();
      STAGEB(u0 + 4, c1); VM4(); RDNXT(c0); MFMA16(2); CPB();
      STAGEB(u0 + 5, c2); VM4(); RDNXT(c1); MFMA16(3); CPB();
    } else {
      STAGEB(62, c2); VM4(); RDNXT(c1); MFMA16(0); CPB();
      STAGEB(63, c0); VM4(); RDNXT(c2); MFMA16(1); CPB();
      VM0();          /* drain B(63) */ RDNXT(c0); MFMA16(2); CPB();
      MFMA16(3);
    }

    // ---- tile epilogue: diag (rare, compile-time indices) + exp2 ----
    if (dWave && ct == ctD) {
#pragma unroll
      for (int m = 0; m < 4; ++m)
#pragma unroll
        for (int r = 0; r < 4; ++r)
          if (lmod == lhalf * 4 + r)
            diag[p * BN_ + D + m * 16 + lmod] = (float)acc[m][m][r] * INVQ;
    }
#pragma unroll
    for (int m = 0; m < 4; ++m)
#pragma unroll
      for (int n = 0; n < 4; ++n)
#pragma unroll
        for (int r = 0; r < 4; ++r)
          rsum[m][r] += __builtin_amdgcn_exp2f((float)acc[m][n][r] * KQ);

    char* t = c0; c0 = c1; c1 = c2; c2 = t;   // slot rotation (4 = 1 mod 3)
  }

  // ---- final: reduce across 16 col-lanes, then atomicAdd ----
#pragma unroll
  for (int m = 0; m < 4; ++m)
#pragma unroll
    for (int r = 0; r < 4; ++r) {
      float v = rsum[m][r];
      v += __shfl_xor(v, 1, 64);
      v += __shfl_xor(v, 2, 64);
      v += __shfl_xor(v, 4, 64);
      v += __shfl_xor(v, 8, 64);
      if (lmod == 0)
        atomicAdd(&sumexp[p * BN_ + D + m * 16 + lhalf * 4 + r], v);
    }
#undef STAGEB
#undef RDNXT
#undef CPB
#undef MFMA16
}

// ---------------- Kernel 3: CE = mean(log(sumexp) - diag) ----------------
__global__ __launch_bounds__(1024) void finalize_kernel(
    const float* __restrict__ sumexp, const float* __restrict__ diag,
    float* __restrict__ out) {
  const int tid = threadIdx.x;
  float s = 0.0f;
  for (int i = tid; i < 2 * BN_; i += 1024) s += logf(sumexp[i]) - diag[i];
#pragma unroll
  for (int mk = 32; mk >= 1; mk >>= 1) s += __shfl_xor(s, mk, 64);
  __shared__ float red[16];
  if ((tid & 63) == 0) red[tid >> 6] = s;
  __syncthreads();
  if (tid == 0) {
    float t = 0.f;
#pragma unroll
    for (int j = 0; j < 16; ++j) t += red[j];
    out[0] = t * (1.0f / (float)BN_);
  }
}

extern "C" void kernel_launch(void* const* d_in, const int* in_sizes, int n_in,
                              void* d_out, int out_size, void* d_ws, size_t ws_size,
                              hipStream_t stream) {
  const float* hf = (const float*)d_in[0];
  const float* lf = (const float*)d_in[1];
  const float* af = (const float*)d_in[2];

  char* ws = (char*)d_ws;
  const size_t nmat = (size_t)BN_ * DK_;                 // 2MB as i8
  unsigned char* qbase = (unsigned char*)ws;             // hq(2MB) lq(2MB) aq(2MB)
  unsigned char* hl = qbase;                             // stacked A [16384][256]
  unsigned char* an = qbase + 2 * nmat;
  float* sumexp = (float*)(ws + 3 * nmat);               // 64 KB [16384]
  float* diag = sumexp + 2 * BN_;                        // 64 KB [16384]

  hipFuncSetAttribute((const void*)gemm_lse_kernel,
                      hipFuncAttributeMaxDynamicSharedMemorySize, 131072);

  norm_kernel<<<(3 * BN_) / 4, 256, 0, stream>>>(hf, lf, af, qbase, sumexp);
  gemm_lse_kernel<<<256, 512, 131072, stream>>>(hl, an, sumexp, diag);
  finalize_kernel<<<1, 1024, 0, stream>>>(sumexp, diag, (float*)d_out);
}

// Round 23
// 63.942 us; speedup vs baseline: 3.6092x; 1.0439x over previous
//
#include <hip/hip_runtime.h>
#include <stdint.h>

#define BN_ 8192
#define DK_ 256
#define LOG2E 1.4426950408889634f
// int8 quantization: q = round(127*x); dot fits i32 exactly
#define INVQ (1.0f / 16129.0f)          // 1/127^2: acc -> natural-units sim
#define KQ   (LOG2E / 16129.0f)          // acc -> log2-units sim

typedef __attribute__((ext_vector_type(4))) float f32x4;
typedef __attribute__((ext_vector_type(4))) int i32x4;

// async global->LDS, 16B/lane; LDS dest wave-uniform base + lane*16, global src per-lane
#define GLD16(gp, lp)                                                   \
  __builtin_amdgcn_global_load_lds(                                     \
      (__attribute__((address_space(1))) void*)(gp),                    \
      (__attribute__((address_space(3))) void*)(lp), 16, 0, 0)

#define BAR() __builtin_amdgcn_s_barrier()
#define VM4() asm volatile("s_waitcnt vmcnt(4)" ::: "memory")
#define VM0() asm volatile("s_waitcnt vmcnt(0)" ::: "memory")

// ---------------- Kernel 1: row-normalize fp32 -> int8 (x127); also zeroes sumexp ----------------
__global__ __launch_bounds__(256) void norm_kernel(
    const float* __restrict__ hf, const float* __restrict__ lf,
    const float* __restrict__ af, unsigned char* __restrict__ qbase,
    float* __restrict__ sumexp) {
  const int tid = threadIdx.x;
  if (blockIdx.x < 16) {   // folded memset of sumexp[16384]
    f32x4 z = {0.f, 0.f, 0.f, 0.f};
    *(f32x4*)(sumexp + blockIdx.x * 1024 + tid * 4) = z;
  }
  const int w = tid >> 6, lane = tid & 63;
  const int grow = blockIdx.x * 4 + w;
  const int m = grow >> 13;
  const int r = grow & (BN_ - 1);
  const float* src = (m == 0) ? hf : (m == 1) ? lf : af;
  unsigned char* dst = qbase + (size_t)m * BN_ * DK_;
  const float4 v = ((const float4*)(src + (size_t)r * DK_))[lane];
  float ss = v.x * v.x + v.y * v.y + v.z * v.z + v.w * v.w;
#pragma unroll
  for (int mk = 32; mk >= 1; mk >>= 1) ss += __shfl_xor(ss, mk, 64);
  const float inv = 127.0f / fmaxf(sqrtf(ss), 1e-8f);
  const int q0 = (int)rintf(v.x * inv), q1 = (int)rintf(v.y * inv);
  const int q2 = (int)rintf(v.z * inv), q3 = (int)rintf(v.w * inv);
  const unsigned pk = (q0 & 255) | ((q1 & 255) << 8) | ((q2 & 255) << 16) |
                      ((unsigned)(q3 & 255) << 24);
  *(unsigned*)(dst + (size_t)r * DK_ + lane * 4) = pk;
}

// ---------------- Kernel 2: barrier-free int8-GEMM + exp2-row-sum + diag ----------------
// R22 structure EXACTLY, minus s_setprio. A/B rationale: with 2 waves/SIMD
// and no phase role-split, setprio(1) around a 326-cyc MFMA cluster starves
// the sibling wave's issue (m190: setprio hurts lockstep GEMM) -- candidate
// cause of the measured ~55% issue-idle (VALUBusy 43% incl. MFMA 26%).
// 256 blocks = 128 mt x 2 cg; 8 waves (2wr x 4wc), wave tile 64x64;
// A panel 32KB staged once (only barrier), afr[4][4] hoisted; per-wave
// 3-slot B LDS queue + register double-buffer, vmcnt(4)-gated, zero
// main-loop barriers. LDS: A 32KB + 8 x 12KB = 128KB.
__global__ __launch_bounds__(512, 2) void gemm_lse_kernel(
    const unsigned char* __restrict__ hl, const unsigned char* __restrict__ an,
    float* __restrict__ sumexp /*[16384]*/, float* __restrict__ diag /*[16384]*/) {
  extern __shared__ char lds[];  // 128KB

  const int tid = threadIdx.x;
  const int lane = tid & 63, w = tid >> 6;
  const int wr = w >> 2, wc = w & 3;
  const int lmod = lane & 15, lhalf = lane >> 4;

  const int bid = blockIdx.x;
  const int swz = (bid & 7) * 32 + (bid >> 3);  // bijective on 256, XCD-grouping
  const int mt = swz >> 1;                      // row panel 0..127 (128 rows each)
  const int cg = swz & 1;                       // col half (16 ct of 256 cols)

  // ---- A cooperative stage: [128 rows][16 slots], phys16 = s ^ (row&15) ----
  const int aswz = 16 * ((tid & 15) ^ ((tid >> 4) & 15));
  const unsigned char* aG = hl + (size_t)(mt * 128 + (tid >> 4)) * DK_ + aswz;
  char* aD = lds + tid * 16;
  GLD16(aG, aD);
  GLD16(aG + 8192, aD + 8192);
  GLD16(aG + 16384, aD + 16384);
  GLD16(aG + 24576, aD + 24576);

  // ---- B private staging constants (R16/R19-verified 64-row slice layout) ----
  const int slog16 = 16 * ((lane & 3) ^ ((lane >> 3) & 3));
  const unsigned char* bB =
      an + (size_t)(cg * 4096 + wc * 64 + (lane >> 2)) * DK_ + slog16;
  char* bw = lds + 32768 + w * 12288;   // this wave's 3-slot region
  char* c0 = bw;                         // slot ptrs rotate per ct
  char* c1 = bw + 4096;
  char* c2 = bw + 8192;

#define STAGEB(uu, DST)                                                  \
  do {                                                                   \
    const int ct_ = (uu) >> 2, ku_ = (uu) & 3;                           \
    const unsigned char* g_ = bB + ct_ * 65536 + ku_ * 64;               \
    char* d_ = (DST) + lane * 16;                                        \
    GLD16(g_, d_);                                                       \
    GLD16(g_ + 4096, d_ + 1024);                                         \
    GLD16(g_ + 8192, d_ + 2048);                                         \
    GLD16(g_ + 12288, d_ + 3072);                                        \
  } while (0)

  STAGEB(0, c0);
  STAGEB(1, c1);
  VM4();   // 12 outstanding (4A+4B0+4B1) -> <=4 left: A and B0 retired
  BAR();   // the kernel's ONLY barrier: A collectively resident

  // ---- hoist all A fragments (R19-verified formulas) ----
  i32x4 afr[4][4];
  {
    const char* aR = lds + (wr * 64 + lmod) * 256;
#pragma unroll
    for (int ku = 0; ku < 4; ++ku)
#pragma unroll
      for (int m = 0; m < 4; ++m)
        afr[ku][m] = *(const i32x4*)(aR + m * 4096 + 16 * ((ku * 4 + lhalf) ^ lmod));
  }

  const int rdoffB = lmod * 64 + 16 * (lhalf ^ ((lmod >> 1) & 3));

  i32x4 bfc[4], bfn[4];
#pragma unroll
  for (int n = 0; n < 4; ++n)
    bfc[n] = *(const i32x4*)(c0 + n * 1024 + rdoffB);   // bf(0)

#define RDNXT(SRC)                                                       \
  _Pragma("unroll") for (int n = 0; n < 4; ++n)                          \
      bfn[n] = *(const i32x4*)((SRC) + n * 1024 + rdoffB)

#define CPB()                                                            \
  _Pragma("unroll") for (int n = 0; n < 4; ++n) bfc[n] = bfn[n]

#define MFMA16(KU)                                                       \
  _Pragma("unroll") for (int m = 0; m < 4; ++m)                          \
  _Pragma("unroll") for (int n = 0; n < 4; ++n)                          \
      acc[m][n] = __builtin_amdgcn_mfma_i32_16x16x64_i8(                 \
          afr[KU][m], bfc[n], acc[m][n], 0, 0, 0)

  // ---- diag geometry (R19-verified) ----
  const int p = mt >> 6;
  const int D = (mt & 63) * 128 + wr * 64;
  const bool dWave = (wc == ((D >> 6) & 3)) && ((D >> 12) == cg);
  const int ctD = (D >> 8) & 15;

  float rsum[4][4];
#pragma unroll
  for (int m = 0; m < 4; ++m)
#pragma unroll
    for (int r = 0; r < 4; ++r) rsum[m][r] = 0.0f;

#pragma unroll 1
  for (int ct = 0; ct < 16; ++ct) {
    i32x4 acc[4][4];
#pragma unroll
    for (int m = 0; m < 4; ++m)
#pragma unroll
      for (int n = 0; n < 4; ++n) acc[m][n] = i32x4{0, 0, 0, 0};

    const int u0 = ct * 4;
    if (ct < 15) {
      STAGEB(u0 + 2, c2); VM4(); RDNXT(c1); MFMA16(0); CPB();
      STAGEB(u0 + 3, c0); VM4(); RDNXT(c2); MFMA16(1); CPB();
      STAGEB(u0 + 4, c1); VM4(); RDNXT(c0); MFMA16(2); CPB();
      STAGEB(u0 + 5, c2); VM4(); RDNXT(c1); MFMA16(3); CPB();
    } else {
      STAGEB(62, c2); VM4(); RDNXT(c1); MFMA16(0); CPB();
      STAGEB(63, c0); VM4(); RDNXT(c2); MFMA16(1); CPB();
      VM0();          /* drain B(63) */ RDNXT(c0); MFMA16(2); CPB();
      MFMA16(3);
    }

    // ---- tile epilogue: diag (rare, compile-time indices) + exp2 ----
    if (dWave && ct == ctD) {
#pragma unroll
      for (int m = 0; m < 4; ++m)
#pragma unroll
        for (int r = 0; r < 4; ++r)
          if (lmod == lhalf * 4 + r)
            diag[p * BN_ + D + m * 16 + lmod] = (float)acc[m][m][r] * INVQ;
    }
#pragma unroll
    for (int m = 0; m < 4; ++m)
#pragma unroll
      for (int n = 0; n < 4; ++n)
#pragma unroll
        for (int r = 0; r < 4; ++r)
          rsum[m][r] += __builtin_amdgcn_exp2f((float)acc[m][n][r] * KQ);

    char* t = c0; c0 = c1; c1 = c2; c2 = t;   // slot rotation (4 = 1 mod 3)
  }

  // ---- final: reduce across 16 col-lanes, then atomicAdd ----
#pragma unroll
  for (int m = 0; m < 4; ++m)
#pragma unroll
    for (int r = 0; r < 4; ++r) {
      float v = rsum[m][r];
      v += __shfl_xor(v, 1, 64);
      v += __shfl_xor(v, 2, 64);
      v += __shfl_xor(v, 4, 64);
      v += __shfl_xor(v, 8, 64);
      if (lmod == 0)
        atomicAdd(&sumexp[p * BN_ + D + m * 16 + lhalf * 4 + r], v);
    }
#undef STAGEB
#undef RDNXT
#undef CPB
#undef MFMA16
}

// ---------------- Kernel 3: CE = mean(log(sumexp) - diag) ----------------
__global__ __launch_bounds__(1024) void finalize_kernel(
    const float* __restrict__ sumexp, const float* __restrict__ diag,
    float* __restrict__ out) {
  const int tid = threadIdx.x;
  float s = 0.0f;
  for (int i = tid; i < 2 * BN_; i += 1024) s += logf(sumexp[i]) - diag[i];
#pragma unroll
  for (int mk = 32; mk >= 1; mk >>= 1) s += __shfl_xor(s, mk, 64);
  __shared__ float red[16];
  if ((tid & 63) == 0) red[tid >> 6] = s;
  __syncthreads();
  if (tid == 0) {
    float t = 0.f;
#pragma unroll
    for (int j = 0; j < 16; ++j) t += red[j];
    out[0] = t * (1.0f / (float)BN_);
  }
}

extern "C" void kernel_launch(void* const* d_in, const int* in_sizes, int n_in,
                              void* d_out, int out_size, void* d_ws, size_t ws_size,
                              hipStream_t stream) {
  const float* hf = (const float*)d_in[0];
  const float* lf = (const float*)d_in[1];
  const float* af = (const float*)d_in[2];

  char* ws = (char*)d_ws;
  const size_t nmat = (size_t)BN_ * DK_;                 // 2MB as i8
  unsigned char* qbase = (unsigned char*)ws;             // hq(2MB) lq(2MB) aq(2MB)
  unsigned char* hl = qbase;                             // stacked A [16384][256]
  unsigned char* an = qbase + 2 * nmat;
  float* sumexp = (float*)(ws + 3 * nmat);               // 64 KB [16384]
  float* diag = sumexp + 2 * BN_;                        // 64 KB [16384]

  hipFuncSetAttribute((const void*)gemm_lse_kernel,
                      hipFuncAttributeMaxDynamicSharedMemorySize, 131072);

  norm_kernel<<<(3 * BN_) / 4, 256, 0, stream>>>(hf, lf, af, qbase, sumexp);
  gemm_lse_kernel<<<256, 512, 131072, stream>>>(hl, an, sumexp, diag);
  finalize_kernel<<<1, 1024, 0, stream>>>(sumexp, diag, (float*)d_out);
}